// Round 5
// baseline (395.841 us; speedup 1.0000x reference)
//
#include <hip/hip_runtime.h>

// MGNConv round 5: round-4 algebra (validated) + coalesced epilogue + prefetch.
//   - main GEMM C^T = w2^T @ hs^T, identity c-axis (round-4 verbatim indices).
//   - epilogue: fold -> wave-private LDS bounce -> coalesced stores + row-
//     coalesced atomics (8 consecutive lanes cover one e_sum row -> HW merge).
//   - one-stage register prefetch of next tile's ei/x/attr/emb.

typedef __attribute__((ext_vector_type(8))) short short8;
typedef __attribute__((ext_vector_type(4))) float floatx4;

__device__ inline unsigned short f2bf(float f) {       // RNE
    union { float f; unsigned u; } v; v.f = f;
    unsigned r = v.u + 0x7FFFu + ((v.u >> 16) & 1u);
    return (unsigned short)(r >> 16);
}

constexpr int TB    = 768;   // 12 waves, 3 waves/SIMD
constexpr int NBLK  = 256;
constexpr int HS_LD = 72;    // hs row stride (u16)
constexpr int SC_LD = 10;    // epilogue scratch row stride (f32)

struct TilePre {
    int    vj[2];
    float4 xi0[2], xi1[2], xj0[2], xj1[2];
    float4 a4[2];
    float4 e0[2], e1[2];
};

__device__ inline TilePre load_tile(int base, int m16, int q,
                                    const float* __restrict__ x,
                                    const int* __restrict__ ei,
                                    const float* __restrict__ attr,
                                    const float* __restrict__ emb, int E)
{
    TilePre P;
    #pragma unroll
    for (int s = 0; s < 2; ++s) {
        const int e  = base + s * 16 + m16;
        const int vi = ei[e];
        const int vj = ei[E + e];
        P.vj[s]  = vj;
        P.xi0[s] = *(const float4*)(x + (size_t)vi * 8);
        P.xi1[s] = *(const float4*)(x + (size_t)vi * 8 + 4);
        P.xj0[s] = *(const float4*)(x + (size_t)vj * 8);
        P.xj1[s] = *(const float4*)(x + (size_t)vj * 8 + 4);
        P.a4[s]  = *(const float4*)(attr + (size_t)e * 4);
        if (q < 2) {
            P.e0[s] = *(const float4*)(emb + (size_t)e * 16 + 8 * q);
            P.e1[s] = *(const float4*)(emb + (size_t)e * 16 + 8 * q + 4);
        } else {
            P.e0[s] = make_float4(0.f, 0.f, 0.f, 0.f);
            P.e1[s] = make_float4(0.f, 0.f, 0.f, 0.f);
        }
    }
    return P;
}

__global__ __launch_bounds__(TB, 3) void edge_kernel(
    const float* __restrict__ x,      // [N,8]
    const int*   __restrict__ ei,     // [2,E]
    const float* __restrict__ attr,   // [E,4]
    const float* __restrict__ emb,    // [E,16]
    const float* __restrict__ w1,     // [16,64]
    const float* __restrict__ w2,     // [64,512]
    float* __restrict__ edge_out,     // [E,8]
    float* __restrict__ e_sum,        // [N,8] pre-zeroed
    int E)
{
    __shared__ __align__(16) unsigned short s_w2n[32768];           // 64 KB
    __shared__ __align__(16) unsigned short s_hsA[12 * 32 * HS_LD]; // 54 KB
    __shared__ __align__(16) int            s_vjA[12 * 32];

    const int tid  = threadIdx.x;
    const int lane = tid & 63;
    const int wave = tid >> 6;
    const int m16  = lane & 15;
    const int q    = lane >> 4;
    const int qk   = q & 1;      // k_out half
    const int par  = q >> 1;     // ab parity

    // ---- stage w2 (bf16) in A-fragment-native order (round-4 verbatim) ----
    for (int idx = tid; idx < 32768; idx += TB) {
        const int j  = idx & 7;
        const int L  = (idx >> 3) & 63;
        const int th = idx >> 9;             // t*2 + h
        s_w2n[idx] = f2bf(w2[(32 * (th & 1) + 8 * (L >> 4) + j) * 512
                             + 16 * (th >> 1) + (L & 15)]);
    }

    // ---- layer-1 w1 B-fragments (round-4 verbatim) ----
    short8 w1f[4];
    #pragma unroll
    for (int ct = 0; ct < 4; ++ct) {
        short8 f;
        #pragma unroll
        for (int j = 0; j < 8; ++j)
            f[j] = (q < 2) ? (short)f2bf(w1[(8 * q + j) * 64 + 16 * ct + m16])
                           : (short)0;
        w1f[ct] = f;
    }
    __syncthreads();   // protects s_w2n; steady loop is wave-private

    unsigned short* hsw = s_hsA + wave * 32 * HS_LD;
    float*          scw = (float*)hsw;          // epilogue scratch (hs is dead)
    int*            vjw = s_vjA + wave * 32;

    const int ntiles = E >> 5;       // 25000
    const int STR    = NBLK * 12;
    int tile = blockIdx.x * 12 + wave;
    if (tile >= ntiles) return;

    TilePre cur = load_tile(tile << 5, m16, q, x, ei, attr, emb, E);

    for (; tile < ntiles; tile += STR) {
        const int base = tile << 5;

        // ---- prefetch next tile (issues now, completes under compute) ----
        TilePre nxt;
        const int tn = tile + STR;
        if (tn < ntiles) nxt = load_tile(tn << 5, m16, q, x, ei, attr, emb, E);

        // ---- unpack cur into compact working regs (cur raw dies here) ----
        int   vja[2];
        float zsr[2][8];
        float atr[2][4];
        short8 a1[2];
        #pragma unroll
        for (int s = 0; s < 2; ++s) {
            vja[s] = cur.vj[s];
            zsr[s][0] = par ? cur.xi0[s].y : cur.xi0[s].x;
            zsr[s][1] = par ? cur.xi0[s].w : cur.xi0[s].z;
            zsr[s][2] = par ? cur.xi1[s].y : cur.xi1[s].x;
            zsr[s][3] = par ? cur.xi1[s].w : cur.xi1[s].z;
            zsr[s][4] = par ? cur.xj0[s].y : cur.xj0[s].x;
            zsr[s][5] = par ? cur.xj0[s].w : cur.xj0[s].z;
            zsr[s][6] = par ? cur.xj1[s].y : cur.xj1[s].x;
            zsr[s][7] = par ? cur.xj1[s].w : cur.xj1[s].z;
            atr[s][0] = cur.a4[s].x; atr[s][1] = cur.a4[s].y;
            atr[s][2] = cur.a4[s].z; atr[s][3] = cur.a4[s].w;
            a1[s][0]=(short)f2bf(cur.e0[s].x); a1[s][1]=(short)f2bf(cur.e0[s].y);
            a1[s][2]=(short)f2bf(cur.e0[s].z); a1[s][3]=(short)f2bf(cur.e0[s].w);
            a1[s][4]=(short)f2bf(cur.e1[s].x); a1[s][5]=(short)f2bf(cur.e1[s].y);
            a1[s][6]=(short)f2bf(cur.e1[s].z); a1[s][7]=(short)f2bf(cur.e1[s].w);
        }

        // ---- layer-1 MFMA -> silu -> hsw (round-4 verbatim indices) ----
        #pragma unroll
        for (int s = 0; s < 2; ++s) {
            #pragma unroll
            for (int ct = 0; ct < 4; ++ct) {
                floatx4 c0 = {0.f, 0.f, 0.f, 0.f};
                c0 = __builtin_amdgcn_mfma_f32_16x16x32_bf16(a1[s], w1f[ct], c0, 0, 0, 0);
                #pragma unroll
                for (int r = 0; r < 4; ++r) {
                    const float u  = c0[r] * 0.25f;
                    const float sv = u * __builtin_amdgcn_rcpf(1.f + __expf(-u))
                                     * (1.0f / 64.0f);
                    hsw[(s * 16 + q * 4 + r) * HS_LD + ct * 16 + m16] = f2bf(sv);
                }
            }
        }

        // ---- hs B-fragments (round-4 verbatim) ----
        short8 hb[2][2];
        #pragma unroll
        for (int s = 0; s < 2; ++s)
            #pragma unroll
            for (int h = 0; h < 2; ++h)
                hb[s][h] = *(const short8*)(hsw + (s * 16 + m16) * HS_LD
                                            + 32 * h + 8 * q);

        float eacc[2][4];
        #pragma unroll
        for (int s = 0; s < 2; ++s)
            #pragma unroll
            for (int r = 0; r < 4; ++r) eacc[s][r] = 0.f;

        // ---- main loop (round-4 verbatim) ----
        #pragma unroll
        for (int g = 0; g < 4; ++g) {
            #pragma unroll
            for (int tt = 0; tt < 8; ++tt) {
                const int t = g * 8 + tt;
                const short8 wA0 = *(const short8*)(s_w2n + (t * 2 + 0) * 512 + lane * 8);
                const short8 wA1 = *(const short8*)(s_w2n + (t * 2 + 1) * 512 + lane * 8);
                const int bi = t & 7;
                #pragma unroll
                for (int s = 0; s < 2; ++s) {
                    floatx4 c = {0.f, 0.f, 0.f, 0.f};
                    c = __builtin_amdgcn_mfma_f32_16x16x32_bf16(wA0, hb[s][0], c, 0, 0, 0);
                    c = __builtin_amdgcn_mfma_f32_16x16x32_bf16(wA1, hb[s][1], c, 0, 0, 0);
                    const float o = atr[s][g] * zsr[s][bi];
                    eacc[s][0] += c[0] * o;
                    eacc[s][1] += c[1] * o;
                    eacc[s][2] += c[2] * o;
                    eacc[s][3] += c[3] * o;
                }
            }
        }

        // ---- fold ab-parities ----
        #pragma unroll
        for (int s = 0; s < 2; ++s)
            #pragma unroll
            for (int r = 0; r < 4; ++r)
                eacc[s][r] += __shfl_xor(eacc[s][r], 32);

        // ---- epilogue bounce: scratch[edge][k], then coalesced passes ----
        if (q < 2) {
            #pragma unroll
            for (int s = 0; s < 2; ++s) {
                float* row = scw + (16 * s + m16) * SC_LD + 4 * qk;
                *(float2*)(row + 0) = make_float2(eacc[s][0], eacc[s][1]);
                *(float2*)(row + 2) = make_float2(eacc[s][2], eacc[s][3]);
                if (q == 0) vjw[16 * s + m16] = vja[s];
            }
        }
        // wave-private LDS: compiler orders write->read via lgkmcnt, no barrier
        #pragma unroll
        for (int p = 0; p < 4; ++p) {
            const int el = 8 * p + (lane >> 3);
            const int k  = lane & 7;
            const float v  = scw[el * SC_LD + k];
            const int vjv  = vjw[el];
            edge_out[(size_t)(base + el) * 8 + k] = v;     // 256B contiguous
            atomicAdd(e_sum + (size_t)vjv * 8 + k, v);     // 8-lane row merge
        }

        cur = nxt;
    }
}

__global__ __launch_bounds__(256) void node_kernel(
    const float* __restrict__ x,       // [N,8]
    const float* __restrict__ e_sum,   // [N,8]
    const float* __restrict__ w_node,  // [8,8,16]
    float* __restrict__ x_out,         // [N,16]
    int N)
{
    __shared__ float s_w[8 * 8 * 16];
    for (int idx = threadIdx.x; idx < 1024; idx += 256) s_w[idx] = w_node[idx];
    __syncthreads();

    const int n = blockIdx.x * 256 + threadIdx.x;
    if (n >= N) return;

    float xa[8], eb[8];
    #pragma unroll
    for (int a = 0; a < 8; ++a) xa[a] = x[(size_t)n * 8 + a];
    #pragma unroll
    for (int b = 0; b < 8; ++b) eb[b] = e_sum[(size_t)n * 8 + b];

    float out[16];
    #pragma unroll
    for (int k = 0; k < 16; ++k) out[k] = 0.f;

    const float4* wv = (const float4*)s_w;
    #pragma unroll
    for (int a = 0; a < 8; ++a) {
        #pragma unroll
        for (int b = 0; b < 8; ++b) {
            const float t = xa[a] * eb[b] * 0.125f;
            #pragma unroll
            for (int k4 = 0; k4 < 4; ++k4) {
                const float4 w = wv[(a * 8 + b) * 4 + k4];
                out[k4 * 4 + 0] = fmaf(t, w.x, out[k4 * 4 + 0]);
                out[k4 * 4 + 1] = fmaf(t, w.y, out[k4 * 4 + 1]);
                out[k4 * 4 + 2] = fmaf(t, w.z, out[k4 * 4 + 2]);
                out[k4 * 4 + 3] = fmaf(t, w.w, out[k4 * 4 + 3]);
            }
        }
    }

    float4* xo = (float4*)(x_out + (size_t)n * 16);
    #pragma unroll
    for (int k4 = 0; k4 < 4; ++k4)
        xo[k4] = make_float4(out[k4 * 4 + 0], out[k4 * 4 + 1],
                             out[k4 * 4 + 2], out[k4 * 4 + 3]);
}

extern "C" void kernel_launch(void* const* d_in, const int* in_sizes, int n_in,
                              void* d_out, int out_size, void* d_ws, size_t ws_size,
                              hipStream_t stream) {
    const float* x      = (const float*)d_in[0];
    const int*   ei     = (const int*)d_in[1];
    const float* attr   = (const float*)d_in[2];
    const float* emb    = (const float*)d_in[3];
    const float* w1     = (const float*)d_in[4];
    const float* w2     = (const float*)d_in[5];
    const float* w_node = (const float*)d_in[6];

    const int N = in_sizes[0] / 8;   // 50000
    const int E = in_sizes[2] / 4;   // 800000

    float* x_out    = (float*)d_out;                   // [N,16]
    float* edge_out = (float*)d_out + (size_t)N * 16;  // [E,8]
    float* e_sum    = (float*)d_ws;                    // [N,8]

    hipMemsetAsync(e_sum, 0, (size_t)N * 8 * sizeof(float), stream);

    edge_kernel<<<NBLK, TB, 0, stream>>>(x, ei, attr, emb, w1, w2,
                                         edge_out, e_sum, E);

    node_kernel<<<(N + 255) / 256, 256, 0, stream>>>(x, e_sum, w_node, x_out, N);
}

// Round 7
// 257.126 us; speedup vs baseline: 1.5395x; 1.5395x over previous
//
#include <hip/hip_runtime.h>

// MGNConv round 7: ONLY validated pieces.
//   - round-4 algebra verbatim: 32-edge tiles, single-phase hs round-trip,
//     swapped main GEMM (C^T = w2^T @ hs^T, identity c), fp32 zsr/atr.
//   - round-5-validated bounce epilogue: fold -> wave-private LDS scratch ->
//     coalesced stores + row-coalesced atomics (8 lanes per e_sum row).
//   - NEW (mechanical only): TB=1024 (16 waves share one w2 copy, 4 w/SIMD).

typedef __attribute__((ext_vector_type(8))) short short8;
typedef __attribute__((ext_vector_type(4))) float floatx4;

__device__ inline unsigned short f2bf(float f) {       // RNE
    union { float f; unsigned u; } v; v.f = f;
    unsigned r = v.u + 0x7FFFu + ((v.u >> 16) & 1u);
    return (unsigned short)(r >> 16);
}

constexpr int TB    = 1024;  // 16 waves, 4 waves/SIMD
constexpr int NW    = 16;
constexpr int NBLK  = 256;
constexpr int HS_LD = 72;    // hs row stride (u16)
constexpr int SC_LD = 10;    // epilogue scratch row stride (f32)

__global__ __launch_bounds__(TB, 4) void edge_kernel(
    const float* __restrict__ x,      // [N,8]
    const int*   __restrict__ ei,     // [2,E]
    const float* __restrict__ attr,   // [E,4]
    const float* __restrict__ emb,    // [E,16]
    const float* __restrict__ w1,     // [16,64]
    const float* __restrict__ w2,     // [64,512]
    float* __restrict__ edge_out,     // [E,8]
    float* __restrict__ e_sum,        // [N,8] pre-zeroed
    int E)
{
    __shared__ __align__(16) unsigned short s_w2n[32768];           // 64 KB
    __shared__ __align__(16) unsigned short s_hsA[NW * 32 * HS_LD]; // 72 KB
    __shared__ __align__(16) int            s_vjA[NW * 32];         // 2 KB

    const int tid  = threadIdx.x;
    const int lane = tid & 63;
    const int wave = tid >> 6;
    const int m16  = lane & 15;
    const int q    = lane >> 4;
    const int qk   = q & 1;      // k_out half
    const int par  = q >> 1;     // ab parity

    // ---- stage w2 (bf16) in A-fragment-native order (round-4 verbatim) ----
    for (int idx = tid; idx < 32768; idx += TB) {
        const int j  = idx & 7;
        const int L  = (idx >> 3) & 63;
        const int th = idx >> 9;             // t*2 + h
        s_w2n[idx] = f2bf(w2[(32 * (th & 1) + 8 * (L >> 4) + j) * 512
                             + 16 * (th >> 1) + (L & 15)]);
    }

    // ---- layer-1 w1 B-fragments (round-4 verbatim) ----
    short8 w1f[4];
    #pragma unroll
    for (int ct = 0; ct < 4; ++ct) {
        short8 f;
        #pragma unroll
        for (int j = 0; j < 8; ++j)
            f[j] = (q < 2) ? (short)f2bf(w1[(8 * q + j) * 64 + 16 * ct + m16])
                           : (short)0;
        w1f[ct] = f;
    }
    __syncthreads();   // protects s_w2n; steady loop is wave-private

    unsigned short* hsw = s_hsA + wave * 32 * HS_LD;
    float*          scw = (float*)hsw;          // epilogue scratch (hs dead)
    int*            vjw = s_vjA + wave * 32;

    const int ntiles = E >> 5;   // 32-edge tiles: 25000
    for (int tile = blockIdx.x * NW + wave; tile < ntiles; tile += NBLK * NW) {
        const int base = tile << 5;

        int   vja[2];
        float zsr[2][8];   // parity-selected z comps (fp32)
        float atr[2][4];   // attr (fp32)

        #pragma unroll
        for (int s = 0; s < 2; ++s) {
            const int e  = base + s * 16 + m16;
            const int vi = ei[e];
            const int vj = ei[E + e];
            vja[s] = vj;

            const float4 xi0 = *(const float4*)(x + (size_t)vi * 8);
            const float4 xi1 = *(const float4*)(x + (size_t)vi * 8 + 4);
            const float4 xj0 = *(const float4*)(x + (size_t)vj * 8);
            const float4 xj1 = *(const float4*)(x + (size_t)vj * 8 + 4);
            zsr[s][0] = par ? xi0.y : xi0.x;  zsr[s][1] = par ? xi0.w : xi0.z;
            zsr[s][2] = par ? xi1.y : xi1.x;  zsr[s][3] = par ? xi1.w : xi1.z;
            zsr[s][4] = par ? xj0.y : xj0.x;  zsr[s][5] = par ? xj0.w : xj0.z;
            zsr[s][6] = par ? xj1.y : xj1.x;  zsr[s][7] = par ? xj1.w : xj1.z;

            const float4 a4 = *(const float4*)(attr + (size_t)e * 4);
            atr[s][0] = a4.x; atr[s][1] = a4.y;
            atr[s][2] = a4.z; atr[s][3] = a4.w;

            // ---- layer-1 A fragment (emb), round-4 verbatim ----
            short8 a1;
            if (q < 2) {
                const float* ep = emb + (size_t)e * 16 + 8 * q;
                const float4 u0 = *(const float4*)ep;
                const float4 u1 = *(const float4*)(ep + 4);
                a1[0]=(short)f2bf(u0.x); a1[1]=(short)f2bf(u0.y);
                a1[2]=(short)f2bf(u0.z); a1[3]=(short)f2bf(u0.w);
                a1[4]=(short)f2bf(u1.x); a1[5]=(short)f2bf(u1.y);
                a1[6]=(short)f2bf(u1.z); a1[7]=(short)f2bf(u1.w);
            } else {
                #pragma unroll
                for (int j = 0; j < 8; ++j) a1[j] = 0;
            }

            // ---- layer-1 MFMA -> silu -> hsw (round-4 verbatim) ----
            #pragma unroll
            for (int ct = 0; ct < 4; ++ct) {
                floatx4 c0 = {0.f, 0.f, 0.f, 0.f};
                c0 = __builtin_amdgcn_mfma_f32_16x16x32_bf16(a1, w1f[ct], c0, 0, 0, 0);
                #pragma unroll
                for (int r = 0; r < 4; ++r) {
                    const float u  = c0[r] * 0.25f;              // /sqrt(16)
                    const float sv = u * __builtin_amdgcn_rcpf(1.f + __expf(-u))
                                     * (1.0f / 64.0f);
                    hsw[(s * 16 + q * 4 + r) * HS_LD + ct * 16 + m16] = f2bf(sv);
                }
            }
        }

        // ---- hs B-fragments (round-4 verbatim) ----
        short8 hb[2][2];
        #pragma unroll
        for (int s = 0; s < 2; ++s)
            #pragma unroll
            for (int h = 0; h < 2; ++h)
                hb[s][h] = *(const short8*)(hsw + (s * 16 + m16) * HS_LD
                                            + 32 * h + 8 * q);

        float eacc[2][4];
        #pragma unroll
        for (int s = 0; s < 2; ++s)
            #pragma unroll
            for (int r = 0; r < 4; ++r) eacc[s][r] = 0.f;

        // ---- main loop (round-4 verbatim) ----
        #pragma unroll
        for (int g = 0; g < 4; ++g) {
            #pragma unroll
            for (int tt = 0; tt < 8; ++tt) {
                const int t = g * 8 + tt;
                const short8 wA0 = *(const short8*)(s_w2n + (t * 2 + 0) * 512 + lane * 8);
                const short8 wA1 = *(const short8*)(s_w2n + (t * 2 + 1) * 512 + lane * 8);
                const int bi = t & 7;
                #pragma unroll
                for (int s = 0; s < 2; ++s) {
                    floatx4 c = {0.f, 0.f, 0.f, 0.f};
                    c = __builtin_amdgcn_mfma_f32_16x16x32_bf16(wA0, hb[s][0], c, 0, 0, 0);
                    c = __builtin_amdgcn_mfma_f32_16x16x32_bf16(wA1, hb[s][1], c, 0, 0, 0);
                    const float o = atr[s][g] * zsr[s][bi];
                    eacc[s][0] += c[0] * o;
                    eacc[s][1] += c[1] * o;
                    eacc[s][2] += c[2] * o;
                    eacc[s][3] += c[3] * o;
                }
            }
        }

        // ---- fold ab-parities (lane bit 5) ----
        #pragma unroll
        for (int s = 0; s < 2; ++s)
            #pragma unroll
            for (int r = 0; r < 4; ++r)
                eacc[s][r] += __shfl_xor(eacc[s][r], 32);

        // ---- bounce epilogue (round-5 validated) ----
        if (q < 2) {
            #pragma unroll
            for (int s = 0; s < 2; ++s) {
                float* row = scw + (16 * s + m16) * SC_LD + 4 * qk;
                *(float2*)(row + 0) = make_float2(eacc[s][0], eacc[s][1]);
                *(float2*)(row + 2) = make_float2(eacc[s][2], eacc[s][3]);
                if (q == 0) vjw[16 * s + m16] = vja[s];
            }
        }
        // wave-private LDS write->read (validated in round 5)
        #pragma unroll
        for (int p = 0; p < 4; ++p) {
            const int el = 8 * p + (lane >> 3);
            const int k  = lane & 7;
            const float v = scw[el * SC_LD + k];
            const int vjv = vjw[el];
            edge_out[(size_t)(base + el) * 8 + k] = v;     // 256B contiguous
            atomicAdd(e_sum + (size_t)vjv * 8 + k, v);     // 8-lane row merge
        }
    }
}

__global__ __launch_bounds__(256) void node_kernel(
    const float* __restrict__ x,       // [N,8]
    const float* __restrict__ e_sum,   // [N,8]
    const float* __restrict__ w_node,  // [8,8,16]
    float* __restrict__ x_out,         // [N,16]
    int N)
{
    __shared__ float s_w[8 * 8 * 16];
    for (int idx = threadIdx.x; idx < 1024; idx += 256) s_w[idx] = w_node[idx];
    __syncthreads();

    const int n = blockIdx.x * 256 + threadIdx.x;
    if (n >= N) return;

    float xa[8], eb[8];
    #pragma unroll
    for (int a = 0; a < 8; ++a) xa[a] = x[(size_t)n * 8 + a];
    #pragma unroll
    for (int b = 0; b < 8; ++b) eb[b] = e_sum[(size_t)n * 8 + b];

    float out[16];
    #pragma unroll
    for (int k = 0; k < 16; ++k) out[k] = 0.f;

    const float4* wv = (const float4*)s_w;
    #pragma unroll
    for (int a = 0; a < 8; ++a) {
        #pragma unroll
        for (int b = 0; b < 8; ++b) {
            const float t = xa[a] * eb[b] * 0.125f;
            #pragma unroll
            for (int k4 = 0; k4 < 4; ++k4) {
                const float4 w = wv[(a * 8 + b) * 4 + k4];
                out[k4 * 4 + 0] = fmaf(t, w.x, out[k4 * 4 + 0]);
                out[k4 * 4 + 1] = fmaf(t, w.y, out[k4 * 4 + 1]);
                out[k4 * 4 + 2] = fmaf(t, w.z, out[k4 * 4 + 2]);
                out[k4 * 4 + 3] = fmaf(t, w.w, out[k4 * 4 + 3]);
            }
        }
    }

    float4* xo = (float4*)(x_out + (size_t)n * 16);
    #pragma unroll
    for (int k4 = 0; k4 < 4; ++k4)
        xo[k4] = make_float4(out[k4 * 4 + 0], out[k4 * 4 + 1],
                             out[k4 * 4 + 2], out[k4 * 4 + 3]);
}

extern "C" void kernel_launch(void* const* d_in, const int* in_sizes, int n_in,
                              void* d_out, int out_size, void* d_ws, size_t ws_size,
                              hipStream_t stream) {
    const float* x      = (const float*)d_in[0];
    const int*   ei     = (const int*)d_in[1];
    const float* attr   = (const float*)d_in[2];
    const float* emb    = (const float*)d_in[3];
    const float* w1     = (const float*)d_in[4];
    const float* w2     = (const float*)d_in[5];
    const float* w_node = (const float*)d_in[6];

    const int N = in_sizes[0] / 8;   // 50000
    const int E = in_sizes[2] / 4;   // 800000

    float* x_out    = (float*)d_out;                   // [N,16]
    float* edge_out = (float*)d_out + (size_t)N * 16;  // [E,8]
    float* e_sum    = (float*)d_ws;                    // [N,8]

    hipMemsetAsync(e_sum, 0, (size_t)N * 8 * sizeof(float), stream);

    edge_kernel<<<NBLK, TB, 0, stream>>>(x, ei, attr, emb, w1, w2,
                                         edge_out, e_sum, E);

    node_kernel<<<(N + 255) / 256, 256, 0, stream>>>(x, e_sum, w_node, x_out, N);
}